// Round 1
// baseline (2903.136 us; speedup 1.0000x reference)
//
#include <hip/hip_runtime.h>
#include <hip/hip_bf16.h>
#include <math.h>

#define N_NODES 20000
#define N_EDGES 640000
#define FIN_D   256
#define HID_D   512
#define TOPK    1000

// ---------------- CSR build ----------------
__global__ void hist_kernel(const int* __restrict__ dst, int* __restrict__ deg, int E) {
    int e = blockIdx.x * blockDim.x + threadIdx.x;
    if (e < E) atomicAdd(&deg[dst[e]], 1);
}

// single block, 256 threads: exclusive scan of cursor(deg) -> row_start, cursor := row_start
__global__ void scan_kernel(int* __restrict__ cursor, int* __restrict__ row_start, int n) {
    __shared__ int tile[256];
    int tid = threadIdx.x;
    int running = 0;
    for (int t0 = 0; t0 < n; t0 += 256) {
        int i = t0 + tid;
        int v = (i < n) ? cursor[i] : 0;
        tile[tid] = v;
        __syncthreads();
        for (int off = 1; off < 256; off <<= 1) {
            int t2 = (tid >= off) ? tile[tid - off] : 0;
            __syncthreads();
            tile[tid] += t2;
            __syncthreads();
        }
        int incl  = tile[tid];
        int total = tile[255];
        if (i < n) { int ex = running + incl - v; row_start[i] = ex; cursor[i] = ex; }
        running += total;
        __syncthreads();
    }
    if (tid == 0) row_start[n] = running;
}

__global__ void fill_kernel(const int* __restrict__ src, const int* __restrict__ dst,
                            int* __restrict__ cursor, int* __restrict__ csr_src, int E) {
    int e = blockIdx.x * blockDim.x + threadIdx.x;
    if (e < E) { int p = atomicAdd(&cursor[dst[e]], 1); csr_src[p] = src[e]; }
}

// ---------------- GIN aggregation: h[i] = x[i] + sum_{j->i} x[j] ----------------
template<int D>
__global__ void agg_kernel(const float* __restrict__ x, const int* __restrict__ row_start,
                           const int* __restrict__ csr_src, float* __restrict__ h) {
    int i = blockIdx.x;
    int t = threadIdx.x;                 // D/4 threads
    const float4* X = (const float4*)x;
    float4 acc = X[(size_t)i * (D / 4) + t];
    int s = row_start[i], e = row_start[i + 1];
    for (int p = s; p < e; ++p) {
        int srcn = csr_src[p];
        float4 v = X[(size_t)srcn * (D / 4) + t];
        acc.x += v.x; acc.y += v.y; acc.z += v.z; acc.w += v.w;
    }
    ((float4*)h)[(size_t)i * (D / 4) + t] = acc;
}

// ---------------- fp32 tiled GEMM: C = act(A[M,K] @ W[K,N] + bias) ----------------
// BM=128, BN=64, BK=16, 256 threads, 8x4 per thread
template<bool RELU>
__launch_bounds__(256)
__global__ void gemm_kernel(const float* __restrict__ A, const float* __restrict__ W,
                            const float* __restrict__ bias, float* __restrict__ C,
                            int M, int K, int N) {
    const int BM = 128, BN = 64, BK = 16;
    __shared__ float Ast[BK][BM + 4];
    __shared__ float Bs[BK][BN + 4];
    int tid = threadIdx.x;
    int ty = tid >> 4, tx = tid & 15;
    int row0 = blockIdx.x * BM;
    int col0 = blockIdx.y * BN;
    float acc[8][4];
#pragma unroll
    for (int i = 0; i < 8; i++)
#pragma unroll
        for (int j = 0; j < 4; j++) acc[i][j] = 0.f;

    int arow_l = tid >> 2;          // 0..63
    int acg    = (tid & 3) * 4;     // 0,4,8,12
    int brow   = tid >> 4;          // 0..15
    int bcol   = (tid & 15) * 4;    // 0..60

    for (int kt = 0; kt < K; kt += BK) {
#pragma unroll
        for (int l = 0; l < 2; ++l) {
            int rl = arow_l + l * 64;
            int gr = row0 + rl; if (gr >= M) gr = M - 1;
            float4 av = *(const float4*)&A[(size_t)gr * K + kt + acg];
            Ast[acg + 0][rl] = av.x; Ast[acg + 1][rl] = av.y;
            Ast[acg + 2][rl] = av.z; Ast[acg + 3][rl] = av.w;
        }
        float4 bv = *(const float4*)&W[(size_t)(kt + brow) * N + col0 + bcol];
        *(float4*)&Bs[brow][bcol] = bv;
        __syncthreads();
#pragma unroll
        for (int k = 0; k < BK; ++k) {
            float4 b4 = *(float4*)&Bs[k][tx * 4];
            float4 a0 = *(float4*)&Ast[k][ty * 8];
            float4 a1 = *(float4*)&Ast[k][ty * 8 + 4];
            float a[8] = {a0.x, a0.y, a0.z, a0.w, a1.x, a1.y, a1.z, a1.w};
            float b[4] = {b4.x, b4.y, b4.z, b4.w};
#pragma unroll
            for (int i = 0; i < 8; i++)
#pragma unroll
                for (int j = 0; j < 4; j++) acc[i][j] = fmaf(a[i], b[j], acc[i][j]);
        }
        __syncthreads();
    }
    float4 bv = *(const float4*)&bias[col0 + tx * 4];
#pragma unroll
    for (int i = 0; i < 8; i++) {
        int gr = row0 + ty * 8 + i;
        if (gr < M) {
            float4 c;
            c.x = acc[i][0] + bv.x; c.y = acc[i][1] + bv.y;
            c.z = acc[i][2] + bv.z; c.w = acc[i][3] + bv.w;
            if (RELU) {
                c.x = fmaxf(c.x, 0.f); c.y = fmaxf(c.y, 0.f);
                c.z = fmaxf(c.z, 0.f); c.w = fmaxf(c.w, 0.f);
            }
            *(float4*)&C[(size_t)gr * N + col0 + tx * 4] = c;
        }
    }
}

// ---------------- final linear [N,512] @ [512,2] + b : one wave per row ----------------
__global__ void lin_kernel(const float* __restrict__ A, const float* __restrict__ w,
                           const float* __restrict__ b, float* __restrict__ o, int M) {
    int wave = threadIdx.x >> 6;
    int lane = threadIdx.x & 63;
    int row = blockIdx.x * 4 + wave;
    if (row >= M) return;
    const float4* Ar = (const float4*)(A + (size_t)row * 512);
    float s0 = 0.f, s1 = 0.f;
#pragma unroll
    for (int q = 0; q < 2; ++q) {
        float4 a = Ar[lane * 2 + q];
        int base = (lane * 8 + q * 4) * 2;
        s0 = fmaf(a.x, w[base + 0], s0); s1 = fmaf(a.x, w[base + 1], s1);
        s0 = fmaf(a.y, w[base + 2], s0); s1 = fmaf(a.y, w[base + 3], s1);
        s0 = fmaf(a.z, w[base + 4], s0); s1 = fmaf(a.z, w[base + 5], s1);
        s0 = fmaf(a.w, w[base + 6], s0); s1 = fmaf(a.w, w[base + 7], s1);
    }
#pragma unroll
    for (int off = 32; off > 0; off >>= 1) {
        s0 += __shfl_down(s0, off, 64);
        s1 += __shfl_down(s1, off, 64);
    }
    if (lane == 0) { o[row * 2] = s0 + b[0]; o[row * 2 + 1] = s1 + b[1]; }
}

// ---------------- pairwise distance ----------------
__global__ void dist_kernel(const float* __restrict__ o1, const float* __restrict__ o2,
                            float* __restrict__ dist, int n) {
    int i = blockIdx.x * blockDim.x + threadIdx.x;
    if (i < n) {
        float2 a = ((const float2*)o1)[i], b = ((const float2*)o2)[i];
        float d0 = a.x - b.x + 1e-6f, d1 = a.y - b.y + 1e-6f;
        dist[i] = sqrtf(d0 * d0 + d1 * d1);
    }
}

// ---------------- exact rank (strictly-greater count, index tie-break) ----------------
#define JCHUNK 2500
__global__ void rank_kernel(const float* __restrict__ dist, int* __restrict__ rank, int n) {
    __shared__ float ds[JCHUNK];
    int tid = threadIdx.x;
    int j0 = blockIdx.y * JCHUNK;
    for (int idx = tid; idx < JCHUNK; idx += 256) ds[idx] = dist[j0 + idx];
    __syncthreads();
    int i = blockIdx.x * 256 + tid;
    if (i >= n) return;
    float di = dist[i];
    int cnt = 0;
#pragma unroll 4
    for (int jj = 0; jj < JCHUNK; ++jj) {
        float dj = ds[jj];
        int j = j0 + jj;
        cnt += (dj > di) || (dj == di && j < i);
    }
    if (cnt) atomicAdd(&rank[i], cnt);
}

__global__ void scatter_topk(const float* __restrict__ dist, const int* __restrict__ rank,
                             float* __restrict__ vals, int n, int k) {
    int i = blockIdx.x * blockDim.x + threadIdx.x;
    if (i < n) { int r = rank[i]; if (r < k) vals[r] = dist[i]; }
}

// ---------------- head MLP: fc1 -> LN -> relu -> fc2 -> LN -> relu -> fc3 -> sigmoid ----------------
__launch_bounds__(512)
__global__ void head_kernel(const float* __restrict__ vals,
                            const float* __restrict__ fc1_w, const float* __restrict__ fc1_b,
                            const float* __restrict__ ln1_g, const float* __restrict__ ln1_b,
                            const float* __restrict__ fc2_w, const float* __restrict__ fc2_b,
                            const float* __restrict__ ln2_g, const float* __restrict__ ln2_b,
                            const float* __restrict__ fc3_w, const float* __restrict__ fc3_b,
                            float* __restrict__ out) {
    __shared__ float sv[TOPK];
    __shared__ float a1[128];
    __shared__ float red[512];
    __shared__ float s_m, s_r;
    int t = threadIdx.x;
    for (int i = t; i < TOPK; i += 512) sv[i] = vals[i];
    __syncthreads();
    float h1 = 0.f;
    if (t < 128) {
        h1 = fc1_b[t];
        for (int j = 0; j < TOPK; ++j) h1 = fmaf(sv[j], fc1_w[j * 128 + t], h1);
    }
    // LN over 128
    red[t] = (t < 128) ? h1 : 0.f; __syncthreads();
    for (int s = 256; s > 0; s >>= 1) { if (t < s) red[t] += red[t + s]; __syncthreads(); }
    if (t == 0) s_m = red[0] / 128.f;
    __syncthreads();
    float m1 = s_m;
    float dv = (t < 128) ? (h1 - m1) : 0.f;
    red[t] = dv * dv; __syncthreads();
    for (int s = 256; s > 0; s >>= 1) { if (t < s) red[t] += red[t + s]; __syncthreads(); }
    if (t == 0) s_r = rsqrtf(red[0] / 128.f + 1e-5f);
    __syncthreads();
    float r1 = s_r;
    if (t < 128) a1[t] = fmaxf((h1 - m1) * r1 * ln1_g[t] + ln1_b[t], 0.f);
    __syncthreads();
    float h2 = fc2_b[t];
    for (int j = 0; j < 128; ++j) h2 = fmaf(a1[j], fc2_w[j * 512 + t], h2);
    // LN over 512
    red[t] = h2; __syncthreads();
    for (int s = 256; s > 0; s >>= 1) { if (t < s) red[t] += red[t + s]; __syncthreads(); }
    if (t == 0) s_m = red[0] / 512.f;
    __syncthreads();
    float m2 = s_m;
    float d2 = h2 - m2;
    red[t] = d2 * d2; __syncthreads();
    for (int s = 256; s > 0; s >>= 1) { if (t < s) red[t] += red[t + s]; __syncthreads(); }
    if (t == 0) s_r = rsqrtf(red[0] / 512.f + 1e-5f);
    __syncthreads();
    float r2 = s_r;
    float y2 = fmaxf((h2 - m2) * r2 * ln2_g[t] + ln2_b[t], 0.f);
    red[t] = y2 * fc3_w[t]; __syncthreads();
    for (int s = 256; s > 0; s >>= 1) { if (t < s) red[t] += red[t + s]; __syncthreads(); }
    if (t == 0) out[0] = 1.f / (1.f + expf(-(red[0] + fc3_b[0])));
}

extern "C" void kernel_launch(void* const* d_in, const int* in_sizes, int n_in,
                              void* d_out, int out_size, void* d_ws, size_t ws_size,
                              hipStream_t stream) {
    const float* x1   = (const float*)d_in[0];
    const int*   ei1  = (const int*)d_in[1];
    const float* x2   = (const float*)d_in[2];
    const int*   ei2  = (const int*)d_in[3];
    const float* w11  = (const float*)d_in[4];
    const float* b11  = (const float*)d_in[5];
    const float* w12  = (const float*)d_in[6];
    const float* b12  = (const float*)d_in[7];
    const float* w21  = (const float*)d_in[8];
    const float* b21  = (const float*)d_in[9];
    const float* w22  = (const float*)d_in[10];
    const float* b22  = (const float*)d_in[11];
    const float* w31  = (const float*)d_in[12];
    const float* b31  = (const float*)d_in[13];
    const float* w32  = (const float*)d_in[14];
    const float* b32  = (const float*)d_in[15];
    const float* lw   = (const float*)d_in[16];
    const float* lb   = (const float*)d_in[17];
    const float* fc1w = (const float*)d_in[18];
    const float* fc1b = (const float*)d_in[19];
    const float* ln1g = (const float*)d_in[20];
    const float* ln1b = (const float*)d_in[21];
    const float* fc2w = (const float*)d_in[22];
    const float* fc2b = (const float*)d_in[23];
    const float* ln2g = (const float*)d_in[24];
    const float* ln2b = (const float*)d_in[25];
    const float* fc3w = (const float*)d_in[26];
    const float* fc3b = (const float*)d_in[27];

    char* ws = (char*)d_ws;
    size_t off = 0;
    auto alloc = [&](size_t bytes) -> void* {
        void* p = ws + off;
        off += (bytes + 255) & ~(size_t)255;
        return p;
    };
    float* P0        = (float*)alloc((size_t)N_NODES * HID_D * 4);
    float* P1        = (float*)alloc((size_t)N_NODES * HID_D * 4);
    float* o1        = (float*)alloc((size_t)N_NODES * 2 * 4);
    float* o2        = (float*)alloc((size_t)N_NODES * 2 * 4);
    float* dist      = (float*)alloc((size_t)N_NODES * 4);
    float* vals      = (float*)alloc((size_t)TOPK * 4);
    int*   rank      = (int*)alloc((size_t)N_NODES * 4);
    int*   row_start = (int*)alloc((size_t)(N_NODES + 1) * 4);
    int*   cursor    = (int*)alloc((size_t)N_NODES * 4);
    int*   csr_src   = (int*)alloc((size_t)N_EDGES * 4);

    dim3 gemm_grid((N_NODES + 127) / 128, HID_D / 64);

    for (int g = 0; g < 2; ++g) {
        const float* xg  = g ? x2 : x1;
        const int*   ei  = g ? ei2 : ei1;
        const int*   srcv = ei;
        const int*   dstv = ei + N_EDGES;
        float* og = g ? o2 : o1;

        hipMemsetAsync(cursor, 0, N_NODES * sizeof(int), stream);
        hist_kernel<<<(N_EDGES + 255) / 256, 256, 0, stream>>>(dstv, cursor, N_EDGES);
        scan_kernel<<<1, 256, 0, stream>>>(cursor, row_start, N_NODES);
        fill_kernel<<<(N_EDGES + 255) / 256, 256, 0, stream>>>(srcv, dstv, cursor, csr_src, N_EDGES);

        // layer 1 (D=256 input)
        agg_kernel<FIN_D><<<N_NODES, FIN_D / 4, 0, stream>>>(xg, row_start, csr_src, P1);
        gemm_kernel<true><<<gemm_grid, 256, 0, stream>>>(P1, w11, b11, P0, N_NODES, FIN_D, HID_D);
        gemm_kernel<true><<<gemm_grid, 256, 0, stream>>>(P0, w12, b12, P1, N_NODES, HID_D, HID_D);
        // layer 2
        agg_kernel<HID_D><<<N_NODES, HID_D / 4, 0, stream>>>(P1, row_start, csr_src, P0);
        gemm_kernel<true><<<gemm_grid, 256, 0, stream>>>(P0, w21, b21, P1, N_NODES, HID_D, HID_D);
        gemm_kernel<true><<<gemm_grid, 256, 0, stream>>>(P1, w22, b22, P0, N_NODES, HID_D, HID_D);
        // layer 3
        agg_kernel<HID_D><<<N_NODES, HID_D / 4, 0, stream>>>(P0, row_start, csr_src, P1);
        gemm_kernel<true><<<gemm_grid, 256, 0, stream>>>(P1, w31, b31, P0, N_NODES, HID_D, HID_D);
        gemm_kernel<true><<<gemm_grid, 256, 0, stream>>>(P0, w32, b32, P1, N_NODES, HID_D, HID_D);
        // final linear [N,512] -> [N,2]
        lin_kernel<<<(N_NODES + 3) / 4, 256, 0, stream>>>(P1, lw, lb, og, N_NODES);
    }

    dist_kernel<<<(N_NODES + 255) / 256, 256, 0, stream>>>(o1, o2, dist, N_NODES);
    hipMemsetAsync(rank, 0, N_NODES * sizeof(int), stream);
    dim3 rank_grid((N_NODES + 255) / 256, N_NODES / JCHUNK);
    rank_kernel<<<rank_grid, 256, 0, stream>>>(dist, rank, N_NODES);
    scatter_topk<<<(N_NODES + 255) / 256, 256, 0, stream>>>(dist, rank, vals, N_NODES, TOPK);
    head_kernel<<<1, 512, 0, stream>>>(vals, fc1w, fc1b, ln1g, ln1b,
                                       fc2w, fc2b, ln2g, ln2b, fc3w, fc3b,
                                       (float*)d_out);
}

// Round 2
// 1396.816 us; speedup vs baseline: 2.0784x; 2.0784x over previous
//
#include <hip/hip_runtime.h>
#include <hip/hip_bf16.h>
#include <math.h>

#define N_NODES 20000
#define N_EDGES 640000
#define FIN_D   256
#define HID_D   512
#define TOPK    1000
#define M_PAD   20096   // 157 * 128

typedef __attribute__((ext_vector_type(8))) short short8;
typedef __attribute__((ext_vector_type(4))) float floatx4;

__device__ __forceinline__ unsigned short f2bf(float f) {
    union { __hip_bfloat16 h; unsigned short u; } cv;
    cv.h = __float2bfloat16(f);
    return cv.u;
}
__device__ __forceinline__ float bflo(unsigned int u) {
    union { unsigned int i; float f; } c; c.i = u << 16; return c.f;
}
__device__ __forceinline__ float bfhi(unsigned int u) {
    union { unsigned int i; float f; } c; c.i = u & 0xffff0000u; return c.f;
}

// ---------------- CSR build ----------------
__global__ void hist_kernel(const int* __restrict__ dst, int* __restrict__ deg, int E) {
    int e = blockIdx.x * blockDim.x + threadIdx.x;
    if (e < E) atomicAdd(&deg[dst[e]], 1);
}

__global__ void scan_kernel(int* __restrict__ cursor, int* __restrict__ row_start, int n) {
    __shared__ int tile[256];
    int tid = threadIdx.x;
    int running = 0;
    for (int t0 = 0; t0 < n; t0 += 256) {
        int i = t0 + tid;
        int v = (i < n) ? cursor[i] : 0;
        tile[tid] = v;
        __syncthreads();
        for (int off = 1; off < 256; off <<= 1) {
            int t2 = (tid >= off) ? tile[tid - off] : 0;
            __syncthreads();
            tile[tid] += t2;
            __syncthreads();
        }
        int incl  = tile[tid];
        int total = tile[255];
        if (i < n) { int ex = running + incl - v; row_start[i] = ex; cursor[i] = ex; }
        running += total;
        __syncthreads();
    }
    if (tid == 0) row_start[n] = running;
}

__global__ void fill_kernel(const int* __restrict__ src, const int* __restrict__ dst,
                            int* __restrict__ cursor, int* __restrict__ csr_src, int E) {
    int e = blockIdx.x * blockDim.x + threadIdx.x;
    if (e < E) { int p = atomicAdd(&cursor[dst[e]], 1); csr_src[p] = src[e]; }
}

// ---------------- conversions ----------------
__global__ void convx_kernel(const float* __restrict__ x, unsigned short* __restrict__ xb, int n4) {
    int i = blockIdx.x * 256 + threadIdx.x;
    if (i < n4) {
        float4 f = ((const float4*)x)[i];
        ushort4 u;
        u.x = f2bf(f.x); u.y = f2bf(f.y); u.z = f2bf(f.z); u.w = f2bf(f.w);
        ((ushort4*)xb)[i] = u;
    }
}

// W[K][N] fp32 -> Wt[N][K] bf16 (tiled transpose)
__global__ void convw_kernel(const float* __restrict__ W, unsigned short* __restrict__ Wt,
                             int K, int N) {
    __shared__ float tile[32][33];
    int k0 = blockIdx.x * 32, n0 = blockIdx.y * 32;
    int tx = threadIdx.x & 31, ty = threadIdx.x >> 5;   // ty 0..7
    for (int r = ty; r < 32; r += 8) tile[r][tx] = W[(size_t)(k0 + r) * N + n0 + tx];
    __syncthreads();
    for (int r = ty; r < 32; r += 8)
        Wt[(size_t)(n0 + r) * K + k0 + tx] = f2bf(tile[tx][r]);
}

// ---------------- GIN aggregation (bf16 in/out, fp32 accum) ----------------
template<int D>
__global__ void agg_kernel(const unsigned short* __restrict__ x, const int* __restrict__ row_start,
                           const int* __restrict__ csr_src, unsigned short* __restrict__ h) {
    const int LP = D / 8;            // uint4 chunks per row
    const int NPB = 256 / LP;
    int nid = blockIdx.x * NPB + threadIdx.x / LP;
    int c = threadIdx.x % LP;
    const uint4* X = (const uint4*)x;
    uint4 v = X[(size_t)nid * LP + c];
    float acc[8];
    acc[0] = bflo(v.x); acc[1] = bfhi(v.x);
    acc[2] = bflo(v.y); acc[3] = bfhi(v.y);
    acc[4] = bflo(v.z); acc[5] = bfhi(v.z);
    acc[6] = bflo(v.w); acc[7] = bfhi(v.w);
    int s = row_start[nid], e = row_start[nid + 1];
    for (int p = s; p < e; ++p) {
        int sn = csr_src[p];
        uint4 u = X[(size_t)sn * LP + c];
        acc[0] += bflo(u.x); acc[1] += bfhi(u.x);
        acc[2] += bflo(u.y); acc[3] += bfhi(u.y);
        acc[4] += bflo(u.z); acc[5] += bfhi(u.z);
        acc[6] += bflo(u.w); acc[7] += bfhi(u.w);
    }
    uint4 o;
    o.x = (unsigned)f2bf(acc[0]) | ((unsigned)f2bf(acc[1]) << 16);
    o.y = (unsigned)f2bf(acc[2]) | ((unsigned)f2bf(acc[3]) << 16);
    o.z = (unsigned)f2bf(acc[4]) | ((unsigned)f2bf(acc[5]) << 16);
    o.w = (unsigned)f2bf(acc[6]) | ((unsigned)f2bf(acc[7]) << 16);
    ((uint4*)h)[(size_t)nid * LP + c] = o;
}

// ---------------- bf16 MFMA GEMM: C = relu(A[M,K] @ W[K,N] + bias), bf16 out ----
// A row-major [M_PAD][K] bf16; Wt is W transposed: [N][K] bf16.
// 128x128 tile, BK=32, 256 threads (4 waves, each 64x64).
__launch_bounds__(256)
__global__ void gemm_mfma(const unsigned short* __restrict__ A,
                          const unsigned short* __restrict__ Wt,
                          const float* __restrict__ bias,
                          unsigned short* __restrict__ C,
                          int K, int N) {
    __shared__ unsigned short As[128 * 32];
    __shared__ unsigned short Bs[128 * 32];
    int tid = threadIdx.x;
    int lane = tid & 63;
    int w = tid >> 6;
    int wr = w >> 1, wc = w & 1;
    int row0 = blockIdx.x * 128;
    int col0 = blockIdx.y * 128;
    floatx4 acc[4][4] = {};
    int lr = tid >> 2;            // 0..63: row within 64-row half of tile
    int c8 = (tid & 3) * 8;       // k element offset of this 16B chunk
    const unsigned short* Ag = A + (size_t)row0 * K;
    const unsigned short* Bg = Wt + (size_t)col0 * K;

    for (int kt = 0; kt < K; kt += 32) {
#pragma unroll
        for (int l = 0; l < 2; ++l) {
            int r = l * 64 + lr;
            __builtin_amdgcn_global_load_lds(
                (const __attribute__((address_space(1))) void*)(Ag + (size_t)r * K + kt + c8),
                (__attribute__((address_space(3))) void*)(As + l * 2048 + tid * 8),
                16, 0, 0);
            __builtin_amdgcn_global_load_lds(
                (const __attribute__((address_space(1))) void*)(Bg + (size_t)r * K + kt + c8),
                (__attribute__((address_space(3))) void*)(Bs + l * 2048 + tid * 8),
                16, 0, 0);
        }
        __syncthreads();
        short8 af[4], bf[4];
        int q8 = (lane >> 4) * 8;
#pragma unroll
        for (int i = 0; i < 4; ++i) {
            int m = wr * 64 + i * 16 + (lane & 15);
            af[i] = *(const short8*)&As[m * 32 + q8];
            int n = wc * 64 + i * 16 + (lane & 15);
            bf[i] = *(const short8*)&Bs[n * 32 + q8];
        }
#pragma unroll
        for (int i = 0; i < 4; ++i)
#pragma unroll
            for (int j = 0; j < 4; ++j)
                acc[i][j] = __builtin_amdgcn_mfma_f32_16x16x32_bf16(af[i], bf[j], acc[i][j], 0, 0, 0);
        __syncthreads();
    }
    // epilogue: C/D layout col=lane&15, row=(lane>>4)*4+reg
    int q = lane >> 4;
    int cn = lane & 15;
#pragma unroll
    for (int j = 0; j < 4; ++j) {
        int col = col0 + wc * 64 + j * 16 + cn;
        float bv = bias[col];
#pragma unroll
        for (int i = 0; i < 4; ++i) {
            int rowb = row0 + wr * 64 + i * 16 + q * 4;
#pragma unroll
            for (int r = 0; r < 4; ++r) {
                float vv = fmaxf(acc[i][j][r] + bv, 0.f);
                C[(size_t)(rowb + r) * N + col] = f2bf(vv);
            }
        }
    }
}

// ---------------- final linear [N,512]bf16 @ [512,2]fp32 + b ----------------
__global__ void lin_kernel(const unsigned short* __restrict__ A, const float* __restrict__ w,
                           const float* __restrict__ b, float* __restrict__ o, int M) {
    int wave = threadIdx.x >> 6;
    int lane = threadIdx.x & 63;
    int row = blockIdx.x * 4 + wave;
    if (row >= M) return;
    const uint4* Ar = (const uint4*)(A + (size_t)row * 512);
    uint4 u = Ar[lane];
    float f[8];
    f[0] = bflo(u.x); f[1] = bfhi(u.x); f[2] = bflo(u.y); f[3] = bfhi(u.y);
    f[4] = bflo(u.z); f[5] = bfhi(u.z); f[6] = bflo(u.w); f[7] = bfhi(u.w);
    float s0 = 0.f, s1 = 0.f;
#pragma unroll
    for (int j = 0; j < 8; ++j) {
        int base = (lane * 8 + j) * 2;
        s0 = fmaf(f[j], w[base + 0], s0);
        s1 = fmaf(f[j], w[base + 1], s1);
    }
#pragma unroll
    for (int off = 32; off > 0; off >>= 1) {
        s0 += __shfl_down(s0, off, 64);
        s1 += __shfl_down(s1, off, 64);
    }
    if (lane == 0) { o[row * 2] = s0 + b[0]; o[row * 2 + 1] = s1 + b[1]; }
}

// ---------------- pairwise distance ----------------
__global__ void dist_kernel(const float* __restrict__ o1, const float* __restrict__ o2,
                            float* __restrict__ dist, int n) {
    int i = blockIdx.x * blockDim.x + threadIdx.x;
    if (i < n) {
        float2 a = ((const float2*)o1)[i], b = ((const float2*)o2)[i];
        float d0 = a.x - b.x + 1e-6f, d1 = a.y - b.y + 1e-6f;
        dist[i] = sqrtf(d0 * d0 + d1 * d1);
    }
}

// ---------------- exact rank (strictly-greater count, index tie-break) ----------------
#define JCHUNK 2500
__global__ void rank_kernel(const float* __restrict__ dist, int* __restrict__ rank, int n) {
    __shared__ float ds[JCHUNK];
    int tid = threadIdx.x;
    int j0 = blockIdx.y * JCHUNK;
    for (int idx = tid; idx < JCHUNK; idx += 256) ds[idx] = dist[j0 + idx];
    __syncthreads();
    int i = blockIdx.x * 256 + tid;
    if (i >= n) return;
    float di = dist[i];
    int cnt = 0;
#pragma unroll 4
    for (int jj = 0; jj < JCHUNK; ++jj) {
        float dj = ds[jj];
        int j = j0 + jj;
        cnt += (dj > di) || (dj == di && j < i);
    }
    if (cnt) atomicAdd(&rank[i], cnt);
}

__global__ void scatter_topk(const float* __restrict__ dist, const int* __restrict__ rank,
                             float* __restrict__ vals, int n, int k) {
    int i = blockIdx.x * blockDim.x + threadIdx.x;
    if (i < n) { int r = rank[i]; if (r < k) vals[r] = dist[i]; }
}

// ---------------- head MLP ----------------
__launch_bounds__(512)
__global__ void head_kernel(const float* __restrict__ vals,
                            const float* __restrict__ fc1_w, const float* __restrict__ fc1_b,
                            const float* __restrict__ ln1_g, const float* __restrict__ ln1_b,
                            const float* __restrict__ fc2_w, const float* __restrict__ fc2_b,
                            const float* __restrict__ ln2_g, const float* __restrict__ ln2_b,
                            const float* __restrict__ fc3_w, const float* __restrict__ fc3_b,
                            float* __restrict__ out) {
    __shared__ float sv[TOPK];
    __shared__ float a1[128];
    __shared__ float red[512];
    __shared__ float s_m, s_r;
    int t = threadIdx.x;
    for (int i = t; i < TOPK; i += 512) sv[i] = vals[i];
    __syncthreads();
    float h1 = 0.f;
    if (t < 128) {
        h1 = fc1_b[t];
        for (int j = 0; j < TOPK; ++j) h1 = fmaf(sv[j], fc1_w[j * 128 + t], h1);
    }
    red[t] = (t < 128) ? h1 : 0.f; __syncthreads();
    for (int s = 256; s > 0; s >>= 1) { if (t < s) red[t] += red[t + s]; __syncthreads(); }
    if (t == 0) s_m = red[0] / 128.f;
    __syncthreads();
    float m1 = s_m;
    float dv = (t < 128) ? (h1 - m1) : 0.f;
    red[t] = dv * dv; __syncthreads();
    for (int s = 256; s > 0; s >>= 1) { if (t < s) red[t] += red[t + s]; __syncthreads(); }
    if (t == 0) s_r = rsqrtf(red[0] / 128.f + 1e-5f);
    __syncthreads();
    float r1 = s_r;
    if (t < 128) a1[t] = fmaxf((h1 - m1) * r1 * ln1_g[t] + ln1_b[t], 0.f);
    __syncthreads();
    float h2 = fc2_b[t];
    for (int j = 0; j < 128; ++j) h2 = fmaf(a1[j], fc2_w[j * 512 + t], h2);
    red[t] = h2; __syncthreads();
    for (int s = 256; s > 0; s >>= 1) { if (t < s) red[t] += red[t + s]; __syncthreads(); }
    if (t == 0) s_m = red[0] / 512.f;
    __syncthreads();
    float m2 = s_m;
    float d2 = h2 - m2;
    red[t] = d2 * d2; __syncthreads();
    for (int s = 256; s > 0; s >>= 1) { if (t < s) red[t] += red[t + s]; __syncthreads(); }
    if (t == 0) s_r = rsqrtf(red[0] / 512.f + 1e-5f);
    __syncthreads();
    float r2 = s_r;
    float y2 = fmaxf((h2 - m2) * r2 * ln2_g[t] + ln2_b[t], 0.f);
    red[t] = y2 * fc3_w[t]; __syncthreads();
    for (int s = 256; s > 0; s >>= 1) { if (t < s) red[t] += red[t + s]; __syncthreads(); }
    if (t == 0) out[0] = 1.f / (1.f + expf(-(red[0] + fc3_b[0])));
}

extern "C" void kernel_launch(void* const* d_in, const int* in_sizes, int n_in,
                              void* d_out, int out_size, void* d_ws, size_t ws_size,
                              hipStream_t stream) {
    const float* x1   = (const float*)d_in[0];
    const int*   ei1  = (const int*)d_in[1];
    const float* x2   = (const float*)d_in[2];
    const int*   ei2  = (const int*)d_in[3];
    const float* w11  = (const float*)d_in[4];
    const float* b11  = (const float*)d_in[5];
    const float* w12  = (const float*)d_in[6];
    const float* b12  = (const float*)d_in[7];
    const float* w21  = (const float*)d_in[8];
    const float* b21  = (const float*)d_in[9];
    const float* w22  = (const float*)d_in[10];
    const float* b22  = (const float*)d_in[11];
    const float* w31  = (const float*)d_in[12];
    const float* b31  = (const float*)d_in[13];
    const float* w32  = (const float*)d_in[14];
    const float* b32  = (const float*)d_in[15];
    const float* lw   = (const float*)d_in[16];
    const float* lb   = (const float*)d_in[17];
    const float* fc1w = (const float*)d_in[18];
    const float* fc1b = (const float*)d_in[19];
    const float* ln1g = (const float*)d_in[20];
    const float* ln1b = (const float*)d_in[21];
    const float* fc2w = (const float*)d_in[22];
    const float* fc2b = (const float*)d_in[23];
    const float* ln2g = (const float*)d_in[24];
    const float* ln2b = (const float*)d_in[25];
    const float* fc3w = (const float*)d_in[26];
    const float* fc3b = (const float*)d_in[27];

    char* ws = (char*)d_ws;
    size_t off = 0;
    auto alloc = [&](size_t bytes) -> void* {
        void* p = ws + off;
        off += (bytes + 255) & ~(size_t)255;
        return p;
    };
    unsigned short* XB1 = (unsigned short*)alloc((size_t)M_PAD * FIN_D * 2);
    unsigned short* XB2 = (unsigned short*)alloc((size_t)M_PAD * FIN_D * 2);
    unsigned short* H0  = (unsigned short*)alloc((size_t)M_PAD * HID_D * 2);
    unsigned short* H1  = (unsigned short*)alloc((size_t)M_PAD * HID_D * 2);
    unsigned short* wt11 = (unsigned short*)alloc((size_t)HID_D * FIN_D * 2);
    unsigned short* wt12 = (unsigned short*)alloc((size_t)HID_D * HID_D * 2);
    unsigned short* wt21 = (unsigned short*)alloc((size_t)HID_D * HID_D * 2);
    unsigned short* wt22 = (unsigned short*)alloc((size_t)HID_D * HID_D * 2);
    unsigned short* wt31 = (unsigned short*)alloc((size_t)HID_D * HID_D * 2);
    unsigned short* wt32 = (unsigned short*)alloc((size_t)HID_D * HID_D * 2);
    float* o1        = (float*)alloc((size_t)N_NODES * 2 * 4);
    float* o2        = (float*)alloc((size_t)N_NODES * 2 * 4);
    float* dist      = (float*)alloc((size_t)N_NODES * 4);
    float* vals      = (float*)alloc((size_t)TOPK * 4);
    int*   rank      = (int*)alloc((size_t)N_NODES * 4);
    int*   row_start = (int*)alloc((size_t)(N_NODES + 1) * 4);
    int*   cursor    = (int*)alloc((size_t)N_NODES * 4);
    int*   csr_src   = (int*)alloc((size_t)N_EDGES * 4);

    // weight conversions (once per call)
    {
        dim3 g11(FIN_D / 32, HID_D / 32);
        dim3 g55(HID_D / 32, HID_D / 32);
        convw_kernel<<<g11, 256, 0, stream>>>(w11, wt11, FIN_D, HID_D);
        convw_kernel<<<g55, 256, 0, stream>>>(w12, wt12, HID_D, HID_D);
        convw_kernel<<<g55, 256, 0, stream>>>(w21, wt21, HID_D, HID_D);
        convw_kernel<<<g55, 256, 0, stream>>>(w22, wt22, HID_D, HID_D);
        convw_kernel<<<g55, 256, 0, stream>>>(w31, wt31, HID_D, HID_D);
        convw_kernel<<<g55, 256, 0, stream>>>(w32, wt32, HID_D, HID_D);
        int n4 = N_NODES * FIN_D / 4;
        convx_kernel<<<(n4 + 255) / 256, 256, 0, stream>>>(x1, XB1, n4);
        convx_kernel<<<(n4 + 255) / 256, 256, 0, stream>>>(x2, XB2, n4);
    }

    dim3 gemm_grid(M_PAD / 128, HID_D / 128);

    for (int g = 0; g < 2; ++g) {
        const unsigned short* xg = g ? XB2 : XB1;
        const int* ei   = g ? ei2 : ei1;
        const int* srcv = ei;
        const int* dstv = ei + N_EDGES;
        float* og = g ? o2 : o1;

        hipMemsetAsync(cursor, 0, N_NODES * sizeof(int), stream);
        hist_kernel<<<(N_EDGES + 255) / 256, 256, 0, stream>>>(dstv, cursor, N_EDGES);
        scan_kernel<<<1, 256, 0, stream>>>(cursor, row_start, N_NODES);
        fill_kernel<<<(N_EDGES + 255) / 256, 256, 0, stream>>>(srcv, dstv, cursor, csr_src, N_EDGES);

        // layer 1 (D=256 input)
        agg_kernel<FIN_D><<<N_NODES / 8, 256, 0, stream>>>(xg, row_start, csr_src, H0);
        gemm_mfma<<<gemm_grid, 256, 0, stream>>>(H0, wt11, b11, H1, FIN_D, HID_D);
        gemm_mfma<<<gemm_grid, 256, 0, stream>>>(H1, wt12, b12, H0, HID_D, HID_D);
        // layer 2
        agg_kernel<HID_D><<<N_NODES / 4, 256, 0, stream>>>(H0, row_start, csr_src, H1);
        gemm_mfma<<<gemm_grid, 256, 0, stream>>>(H1, wt21, b21, H0, HID_D, HID_D);
        gemm_mfma<<<gemm_grid, 256, 0, stream>>>(H0, wt22, b22, H1, HID_D, HID_D);
        // layer 3
        agg_kernel<HID_D><<<N_NODES / 4, 256, 0, stream>>>(H1, row_start, csr_src, H0);
        gemm_mfma<<<gemm_grid, 256, 0, stream>>>(H0, wt31, b31, H1, HID_D, HID_D);
        gemm_mfma<<<gemm_grid, 256, 0, stream>>>(H1, wt32, b32, H0, HID_D, HID_D);
        // final linear [N,512] -> [N,2]
        lin_kernel<<<(N_NODES + 3) / 4, 256, 0, stream>>>(H0, lw, lb, og, N_NODES);
    }

    dist_kernel<<<(N_NODES + 255) / 256, 256, 0, stream>>>(o1, o2, dist, N_NODES);
    hipMemsetAsync(rank, 0, N_NODES * sizeof(int), stream);
    dim3 rank_grid((N_NODES + 255) / 256, N_NODES / JCHUNK);
    rank_kernel<<<rank_grid, 256, 0, stream>>>(dist, rank, N_NODES);
    scatter_topk<<<(N_NODES + 255) / 256, 256, 0, stream>>>(dist, rank, vals, N_NODES, TOPK);
    head_kernel<<<1, 512, 0, stream>>>(vals, fc1w, fc1b, ln1g, ln1b,
                                       fc2w, fc2b, ln2g, ln2b, fc3w, fc3b,
                                       (float*)d_out);
}

// Round 3
// 1066.628 us; speedup vs baseline: 2.7218x; 1.3096x over previous
//
#include <hip/hip_runtime.h>
#include <hip/hip_bf16.h>
#include <math.h>

#define N1      20000          // nodes per graph
#define NT      40000          // both graphs
#define E1      640000         // edges per graph
#define ET      1280000
#define FIN_D   256
#define HID_D   512
#define TOPK    1000
#define MP      40064          // 313 * 128  (padded M for both graphs)
#define SCAN_NB 157            // ceil(40000/256)

typedef __attribute__((ext_vector_type(8))) short short8;
typedef __attribute__((ext_vector_type(4))) float floatx4;

__device__ __forceinline__ unsigned short f2bf(float f) {
    union { __hip_bfloat16 h; unsigned short u; } cv;
    cv.h = __float2bfloat16(f);
    return cv.u;
}
__device__ __forceinline__ float bflo(unsigned int u) {
    union { unsigned int i; float f; } c; c.i = u << 16; return c.f;
}
__device__ __forceinline__ float bfhi(unsigned int u) {
    union { unsigned int i; float f; } c; c.i = u & 0xffff0000u; return c.f;
}

// ---------------- CSR build (both graphs in one node space) ----------------
__global__ void hist_kernel(const int* __restrict__ ei1, const int* __restrict__ ei2,
                            int* __restrict__ deg) {
    int e = blockIdx.x * blockDim.x + threadIdx.x;
    if (e >= ET) return;
    int d = (e < E1) ? ei1[E1 + e] : (ei2[E1 + (e - E1)] + N1);
    atomicAdd(&deg[d], 1);
}

// scan phase 1: per-block exclusive scan of deg -> tmp, block sums -> bsum
__global__ void scan1_kernel(const int* __restrict__ deg, int* __restrict__ tmp,
                             int* __restrict__ bsum) {
    __shared__ int tile[256];
    int t = threadIdx.x;
    int i = blockIdx.x * 256 + t;
    int v = (i < NT) ? deg[i] : 0;
    tile[t] = v;
    __syncthreads();
    for (int off = 1; off < 256; off <<= 1) {
        int x = (t >= off) ? tile[t - off] : 0;
        __syncthreads();
        tile[t] += x;
        __syncthreads();
    }
    if (i < NT) tmp[i] = tile[t] - v;
    if (t == 255) bsum[blockIdx.x] = tile[255];
}

// scan phase 2: single block scans bsum[0..SCAN_NB) -> boff, writes grand total
__global__ void scan2_kernel(const int* __restrict__ bsum, int* __restrict__ boff,
                             int* __restrict__ row_start) {
    __shared__ int tile[256];
    int t = threadIdx.x;
    int v = (t < SCAN_NB) ? bsum[t] : 0;
    tile[t] = v;
    __syncthreads();
    for (int off = 1; off < 256; off <<= 1) {
        int x = (t >= off) ? tile[t - off] : 0;
        __syncthreads();
        tile[t] += x;
        __syncthreads();
    }
    if (t < SCAN_NB) boff[t] = tile[t] - v;
    if (t == 255) row_start[NT] = tile[255];
}

// scan phase 3: add block offsets, produce row_start and cursor
__global__ void scan3_kernel(const int* __restrict__ tmp, const int* __restrict__ boff,
                             int* __restrict__ row_start, int* __restrict__ cursor) {
    int i = blockIdx.x * 256 + threadIdx.x;
    if (i < NT) {
        int rs = tmp[i] + boff[blockIdx.x];
        row_start[i] = rs;
        cursor[i] = rs;
    }
}

__global__ void fill_kernel(const int* __restrict__ ei1, const int* __restrict__ ei2,
                            int* __restrict__ cursor, int* __restrict__ csr_src) {
    int e = blockIdx.x * blockDim.x + threadIdx.x;
    if (e >= ET) return;
    int s, d;
    if (e < E1) { s = ei1[e]; d = ei1[E1 + e]; }
    else        { int e2 = e - E1; s = ei2[e2] + N1; d = ei2[E1 + e2] + N1; }
    int p = atomicAdd(&cursor[d], 1);
    csr_src[p] = s;
}

// ---------------- conversions ----------------
__global__ void convx_kernel(const float* __restrict__ x, unsigned short* __restrict__ xb, int n4) {
    int i = blockIdx.x * 256 + threadIdx.x;
    if (i < n4) {
        float4 f = ((const float4*)x)[i];
        ushort4 u;
        u.x = f2bf(f.x); u.y = f2bf(f.y); u.z = f2bf(f.z); u.w = f2bf(f.w);
        ((ushort4*)xb)[i] = u;
    }
}

// W[K][N] fp32 -> Wt[N][K] bf16 (tiled transpose)
__global__ void convw_kernel(const float* __restrict__ W, unsigned short* __restrict__ Wt,
                             int K, int N) {
    __shared__ float tile[32][33];
    int k0 = blockIdx.x * 32, n0 = blockIdx.y * 32;
    int tx = threadIdx.x & 31, ty = threadIdx.x >> 5;
    for (int r = ty; r < 32; r += 8) tile[r][tx] = W[(size_t)(k0 + r) * N + n0 + tx];
    __syncthreads();
    for (int r = ty; r < 32; r += 8)
        Wt[(size_t)(n0 + r) * K + k0 + tx] = f2bf(tile[tx][r]);
}

// ---------------- GIN aggregation (bf16 in/out, fp32 accum, MLP-unrolled) ------
#define ACC8(u) do { \
    acc[0] += bflo((u).x); acc[1] += bfhi((u).x); \
    acc[2] += bflo((u).y); acc[3] += bfhi((u).y); \
    acc[4] += bflo((u).z); acc[5] += bfhi((u).z); \
    acc[6] += bflo((u).w); acc[7] += bfhi((u).w); } while (0)

template<int D>
__global__ void agg_kernel(const unsigned short* __restrict__ x, const int* __restrict__ row_start,
                           const int* __restrict__ csr_src, unsigned short* __restrict__ h) {
    const int LP = D / 8;            // uint4 chunks per row
    const int NPB = 256 / LP;
    int nid = blockIdx.x * NPB + threadIdx.x / LP;
    int c = threadIdx.x % LP;
    const uint4* X = (const uint4*)x;
    uint4 v = X[(size_t)nid * LP + c];
    float acc[8];
    acc[0] = bflo(v.x); acc[1] = bfhi(v.x);
    acc[2] = bflo(v.y); acc[3] = bfhi(v.y);
    acc[4] = bflo(v.z); acc[5] = bfhi(v.z);
    acc[6] = bflo(v.w); acc[7] = bfhi(v.w);
    int s = row_start[nid], e = row_start[nid + 1];
    int p = s;
    for (; p + 4 <= e; p += 4) {
        int n0 = csr_src[p], n1 = csr_src[p + 1], n2 = csr_src[p + 2], n3 = csr_src[p + 3];
        uint4 u0 = X[(size_t)n0 * LP + c];
        uint4 u1 = X[(size_t)n1 * LP + c];
        uint4 u2 = X[(size_t)n2 * LP + c];
        uint4 u3 = X[(size_t)n3 * LP + c];
        ACC8(u0); ACC8(u1); ACC8(u2); ACC8(u3);
    }
    for (; p < e; ++p) {
        int sn = csr_src[p];
        uint4 u = X[(size_t)sn * LP + c];
        ACC8(u);
    }
    uint4 o;
    o.x = (unsigned)f2bf(acc[0]) | ((unsigned)f2bf(acc[1]) << 16);
    o.y = (unsigned)f2bf(acc[2]) | ((unsigned)f2bf(acc[3]) << 16);
    o.z = (unsigned)f2bf(acc[4]) | ((unsigned)f2bf(acc[5]) << 16);
    o.w = (unsigned)f2bf(acc[6]) | ((unsigned)f2bf(acc[7]) << 16);
    ((uint4*)h)[(size_t)nid * LP + c] = o;
}

// ---------------- bf16 MFMA GEMM: C = relu(A[MP,K] @ W[K,N] + bias), bf16 out ----
__launch_bounds__(256)
__global__ void gemm_mfma(const unsigned short* __restrict__ A,
                          const unsigned short* __restrict__ Wt,
                          const float* __restrict__ bias,
                          unsigned short* __restrict__ C,
                          int K, int N) {
    __shared__ unsigned short As[128 * 32];
    __shared__ unsigned short Bs[128 * 32];
    int tid = threadIdx.x;
    int lane = tid & 63;
    int w = tid >> 6;
    int wr = w >> 1, wc = w & 1;
    int row0 = blockIdx.x * 128;
    int col0 = blockIdx.y * 128;
    floatx4 acc[4][4] = {};
    int lr = tid >> 2;
    int c8 = (tid & 3) * 8;
    const unsigned short* Ag = A + (size_t)row0 * K;
    const unsigned short* Bg = Wt + (size_t)col0 * K;

    for (int kt = 0; kt < K; kt += 32) {
#pragma unroll
        for (int l = 0; l < 2; ++l) {
            int r = l * 64 + lr;
            __builtin_amdgcn_global_load_lds(
                (const __attribute__((address_space(1))) void*)(Ag + (size_t)r * K + kt + c8),
                (__attribute__((address_space(3))) void*)(As + l * 2048 + tid * 8),
                16, 0, 0);
            __builtin_amdgcn_global_load_lds(
                (const __attribute__((address_space(1))) void*)(Bg + (size_t)r * K + kt + c8),
                (__attribute__((address_space(3))) void*)(Bs + l * 2048 + tid * 8),
                16, 0, 0);
        }
        __syncthreads();
        short8 af[4], bf[4];
        int q8 = (lane >> 4) * 8;
#pragma unroll
        for (int i = 0; i < 4; ++i) {
            int m = wr * 64 + i * 16 + (lane & 15);
            af[i] = *(const short8*)&As[m * 32 + q8];
            int n = wc * 64 + i * 16 + (lane & 15);
            bf[i] = *(const short8*)&Bs[n * 32 + q8];
        }
#pragma unroll
        for (int i = 0; i < 4; ++i)
#pragma unroll
            for (int j = 0; j < 4; ++j)
                acc[i][j] = __builtin_amdgcn_mfma_f32_16x16x32_bf16(af[i], bf[j], acc[i][j], 0, 0, 0);
        __syncthreads();
    }
    int q = lane >> 4;
    int cn = lane & 15;
#pragma unroll
    for (int j = 0; j < 4; ++j) {
        int col = col0 + wc * 64 + j * 16 + cn;
        float bv = bias[col];
#pragma unroll
        for (int i = 0; i < 4; ++i) {
            int rowb = row0 + wr * 64 + i * 16 + q * 4;
#pragma unroll
            for (int r = 0; r < 4; ++r) {
                float vv = fmaxf(acc[i][j][r] + bv, 0.f);
                C[(size_t)(rowb + r) * N + col] = f2bf(vv);
            }
        }
    }
}

// ---------------- final linear [NT,512]bf16 @ [512,2]fp32 + b ----------------
__global__ void lin_kernel(const unsigned short* __restrict__ A, const float* __restrict__ w,
                           const float* __restrict__ b, float* __restrict__ o, int M) {
    int wave = threadIdx.x >> 6;
    int lane = threadIdx.x & 63;
    int row = blockIdx.x * 4 + wave;
    if (row >= M) return;
    const uint4* Ar = (const uint4*)(A + (size_t)row * 512);
    uint4 u = Ar[lane];
    float f[8];
    f[0] = bflo(u.x); f[1] = bfhi(u.x); f[2] = bflo(u.y); f[3] = bfhi(u.y);
    f[4] = bflo(u.z); f[5] = bfhi(u.z); f[6] = bflo(u.w); f[7] = bfhi(u.w);
    float s0 = 0.f, s1 = 0.f;
#pragma unroll
    for (int j = 0; j < 8; ++j) {
        int base = (lane * 8 + j) * 2;
        s0 = fmaf(f[j], w[base + 0], s0);
        s1 = fmaf(f[j], w[base + 1], s1);
    }
#pragma unroll
    for (int off = 32; off > 0; off >>= 1) {
        s0 += __shfl_down(s0, off, 64);
        s1 += __shfl_down(s1, off, 64);
    }
    if (lane == 0) { o[row * 2] = s0 + b[0]; o[row * 2 + 1] = s1 + b[1]; }
}

// ---------------- pairwise distance ----------------
__global__ void dist_kernel(const float* __restrict__ o, float* __restrict__ dist) {
    int i = blockIdx.x * blockDim.x + threadIdx.x;
    if (i < N1) {
        float2 a = ((const float2*)o)[i];
        float2 b = ((const float2*)o)[N1 + i];
        float d0 = a.x - b.x + 1e-6f, d1 = a.y - b.y + 1e-6f;
        dist[i] = sqrtf(d0 * d0 + d1 * d1);
    }
}

// ---------------- radix-select top-k ----------------
// bucket = float_bits >> 19 (order-preserving for non-negative floats), 4096 buckets
__global__ void histd_kernel(const float* __restrict__ dist, int* __restrict__ hist) {
    int i = blockIdx.x * blockDim.x + threadIdx.x;
    if (i < N1) {
        unsigned u = __float_as_uint(dist[i]);
        atomicAdd(&hist[u >> 19], 1);
    }
}

// single block: scan buckets from high to low, find threshold bucket
__global__ void selk_kernel(const int* __restrict__ hist, int* __restrict__ selout) {
    __shared__ int tile[256];
    int t = threadIdx.x;
    int running = 0;
    for (int tb = 0; tb < 16; ++tb) {
        int idx = 4095 - (tb * 256 + t);          // descending
        int v = hist[idx];
        tile[t] = v;
        __syncthreads();
        for (int off = 1; off < 256; off <<= 1) {
            int x = (t >= off) ? tile[t - off] : 0;
            __syncthreads();
            tile[t] += x;
            __syncthreads();
        }
        int incl = running + tile[t];
        if (incl >= TOPK && incl - v < TOPK) selout[0] = idx;   // unique thread
        running += tile[255];
        __syncthreads();
        if (running >= TOPK) break;               // uniform
    }
}

__global__ void compact_kernel(const float* __restrict__ dist, const int* __restrict__ selout,
                               int* __restrict__ nc, float* __restrict__ cd, int* __restrict__ ci) {
    int i = blockIdx.x * blockDim.x + threadIdx.x;
    if (i >= N1) return;
    float d = dist[i];
    int b = (int)(__float_as_uint(d) >> 19);
    if (b >= selout[0]) {
        int p = atomicAdd(nc, 1);
        cd[p] = d;
        ci[p] = i;
    }
}

// exact rank among candidates only; write vals[rank] for rank < K
#define CCH 2048
__global__ void rankc_kernel(const float* __restrict__ cd, const int* __restrict__ ci,
                             const int* __restrict__ nc_p, float* __restrict__ vals) {
    __shared__ float ds[CCH];
    __shared__ int   di_[CCH];
    int nc = *nc_p;
    int t = threadIdx.x;
    int q = blockIdx.x * 256 + t;
    float dq = 0.f; int iq = 0;
    if (q < nc) { dq = cd[q]; iq = ci[q]; }
    int cnt = 0;
    for (int c0 = 0; c0 < nc; c0 += CCH) {
        int lim = min(CCH, nc - c0);
        for (int j = t; j < lim; j += 256) { ds[j] = cd[c0 + j]; di_[j] = ci[c0 + j]; }
        __syncthreads();
        if (q < nc) {
            for (int j = 0; j < lim; ++j) {
                float dj = ds[j];
                cnt += (dj > dq) || (dj == dq && di_[j] < iq);
            }
        }
        __syncthreads();
    }
    if (q < nc && cnt < TOPK) vals[cnt] = dq;
}

// ---------------- head MLP ----------------
__launch_bounds__(512)
__global__ void head_kernel(const float* __restrict__ vals,
                            const float* __restrict__ fc1_w, const float* __restrict__ fc1_b,
                            const float* __restrict__ ln1_g, const float* __restrict__ ln1_b,
                            const float* __restrict__ fc2_w, const float* __restrict__ fc2_b,
                            const float* __restrict__ ln2_g, const float* __restrict__ ln2_b,
                            const float* __restrict__ fc3_w, const float* __restrict__ fc3_b,
                            float* __restrict__ out) {
    __shared__ float sv[TOPK];
    __shared__ float a1[128];
    __shared__ float red[512];
    __shared__ float s_m, s_r;
    int t = threadIdx.x;
    for (int i = t; i < TOPK; i += 512) sv[i] = vals[i];
    __syncthreads();
    float h1 = 0.f;
    if (t < 128) {
        h1 = fc1_b[t];
        for (int j = 0; j < TOPK; ++j) h1 = fmaf(sv[j], fc1_w[j * 128 + t], h1);
    }
    red[t] = (t < 128) ? h1 : 0.f; __syncthreads();
    for (int s = 256; s > 0; s >>= 1) { if (t < s) red[t] += red[t + s]; __syncthreads(); }
    if (t == 0) s_m = red[0] / 128.f;
    __syncthreads();
    float m1 = s_m;
    float dv = (t < 128) ? (h1 - m1) : 0.f;
    red[t] = dv * dv; __syncthreads();
    for (int s = 256; s > 0; s >>= 1) { if (t < s) red[t] += red[t + s]; __syncthreads(); }
    if (t == 0) s_r = rsqrtf(red[0] / 128.f + 1e-5f);
    __syncthreads();
    float r1 = s_r;
    if (t < 128) a1[t] = fmaxf((h1 - m1) * r1 * ln1_g[t] + ln1_b[t], 0.f);
    __syncthreads();
    float h2 = fc2_b[t];
    for (int j = 0; j < 128; ++j) h2 = fmaf(a1[j], fc2_w[j * 512 + t], h2);
    red[t] = h2; __syncthreads();
    for (int s = 256; s > 0; s >>= 1) { if (t < s) red[t] += red[t + s]; __syncthreads(); }
    if (t == 0) s_m = red[0] / 512.f;
    __syncthreads();
    float m2 = s_m;
    float d2 = h2 - m2;
    red[t] = d2 * d2; __syncthreads();
    for (int s = 256; s > 0; s >>= 1) { if (t < s) red[t] += red[t + s]; __syncthreads(); }
    if (t == 0) s_r = rsqrtf(red[0] / 512.f + 1e-5f);
    __syncthreads();
    float r2 = s_r;
    float y2 = fmaxf((h2 - m2) * r2 * ln2_g[t] + ln2_b[t], 0.f);
    red[t] = y2 * fc3_w[t]; __syncthreads();
    for (int s = 256; s > 0; s >>= 1) { if (t < s) red[t] += red[t + s]; __syncthreads(); }
    if (t == 0) out[0] = 1.f / (1.f + expf(-(red[0] + fc3_b[0])));
}

extern "C" void kernel_launch(void* const* d_in, const int* in_sizes, int n_in,
                              void* d_out, int out_size, void* d_ws, size_t ws_size,
                              hipStream_t stream) {
    const float* x1   = (const float*)d_in[0];
    const int*   ei1  = (const int*)d_in[1];
    const float* x2   = (const float*)d_in[2];
    const int*   ei2  = (const int*)d_in[3];
    const float* w11  = (const float*)d_in[4];
    const float* b11  = (const float*)d_in[5];
    const float* w12  = (const float*)d_in[6];
    const float* b12  = (const float*)d_in[7];
    const float* w21  = (const float*)d_in[8];
    const float* b21  = (const float*)d_in[9];
    const float* w22  = (const float*)d_in[10];
    const float* b22  = (const float*)d_in[11];
    const float* w31  = (const float*)d_in[12];
    const float* b31  = (const float*)d_in[13];
    const float* w32  = (const float*)d_in[14];
    const float* b32  = (const float*)d_in[15];
    const float* lw   = (const float*)d_in[16];
    const float* lb   = (const float*)d_in[17];
    const float* fc1w = (const float*)d_in[18];
    const float* fc1b = (const float*)d_in[19];
    const float* ln1g = (const float*)d_in[20];
    const float* ln1b = (const float*)d_in[21];
    const float* fc2w = (const float*)d_in[22];
    const float* fc2b = (const float*)d_in[23];
    const float* ln2g = (const float*)d_in[24];
    const float* ln2b = (const float*)d_in[25];
    const float* fc3w = (const float*)d_in[26];
    const float* fc3b = (const float*)d_in[27];

    char* ws = (char*)d_ws;
    size_t off = 0;
    auto alloc = [&](size_t bytes) -> void* {
        void* p = ws + off;
        off += (bytes + 255) & ~(size_t)255;
        return p;
    };
    unsigned short* H0  = (unsigned short*)alloc((size_t)MP * HID_D * 2);
    unsigned short* H1  = (unsigned short*)alloc((size_t)MP * HID_D * 2);
    unsigned short* XB  = H1;   // alias: XB dead before gemm1 writes H1
    unsigned short* wt11 = (unsigned short*)alloc((size_t)HID_D * FIN_D * 2);
    unsigned short* wt12 = (unsigned short*)alloc((size_t)HID_D * HID_D * 2);
    unsigned short* wt21 = (unsigned short*)alloc((size_t)HID_D * HID_D * 2);
    unsigned short* wt22 = (unsigned short*)alloc((size_t)HID_D * HID_D * 2);
    unsigned short* wt31 = (unsigned short*)alloc((size_t)HID_D * HID_D * 2);
    unsigned short* wt32 = (unsigned short*)alloc((size_t)HID_D * HID_D * 2);
    float* o         = (float*)alloc((size_t)NT * 2 * 4);
    float* dist      = (float*)alloc((size_t)N1 * 4);
    float* vals      = (float*)alloc((size_t)TOPK * 4);
    int*   row_start = (int*)alloc((size_t)(NT + 1) * 4);
    int*   cursor    = (int*)alloc((size_t)NT * 4);
    int*   deg       = (int*)alloc((size_t)NT * 4);
    int*   scan_tmp  = (int*)alloc((size_t)NT * 4);
    int*   bsum      = (int*)alloc((size_t)SCAN_NB * 4);
    int*   boff      = (int*)alloc((size_t)SCAN_NB * 4);
    int*   csr_src   = (int*)alloc((size_t)ET * 4);
    int*   selblk    = (int*)alloc((size_t)(4096 + 64) * 4);  // hist + nc
    int*   hist      = selblk;
    int*   nc        = selblk + 4096;
    int*   selout    = (int*)alloc(2 * 4);
    float* cd        = (float*)alloc((size_t)N1 * 4);
    int*   ci        = (int*)alloc((size_t)N1 * 4);

    // ---- weight / input conversions ----
    {
        dim3 g11(FIN_D / 32, HID_D / 32);
        dim3 g55(HID_D / 32, HID_D / 32);
        convw_kernel<<<g11, 256, 0, stream>>>(w11, wt11, FIN_D, HID_D);
        convw_kernel<<<g55, 256, 0, stream>>>(w12, wt12, HID_D, HID_D);
        convw_kernel<<<g55, 256, 0, stream>>>(w21, wt21, HID_D, HID_D);
        convw_kernel<<<g55, 256, 0, stream>>>(w22, wt22, HID_D, HID_D);
        convw_kernel<<<g55, 256, 0, stream>>>(w31, wt31, HID_D, HID_D);
        convw_kernel<<<g55, 256, 0, stream>>>(w32, wt32, HID_D, HID_D);
        int n4 = N1 * FIN_D / 4;
        convx_kernel<<<(n4 + 255) / 256, 256, 0, stream>>>(x1, XB, n4);
        convx_kernel<<<(n4 + 255) / 256, 256, 0, stream>>>(x2, XB + (size_t)N1 * FIN_D, n4);
    }

    // ---- CSR build (both graphs, global node ids) ----
    hipMemsetAsync(deg, 0, NT * sizeof(int), stream);
    hist_kernel<<<(ET + 255) / 256, 256, 0, stream>>>(ei1, ei2, deg);
    scan1_kernel<<<SCAN_NB, 256, 0, stream>>>(deg, scan_tmp, bsum);
    scan2_kernel<<<1, 256, 0, stream>>>(bsum, boff, row_start);
    scan3_kernel<<<SCAN_NB, 256, 0, stream>>>(scan_tmp, boff, row_start, cursor);
    fill_kernel<<<(ET + 255) / 256, 256, 0, stream>>>(ei1, ei2, cursor, csr_src);

    // ---- GNN pipeline (both graphs batched) ----
    dim3 gemm_grid(MP / 128, HID_D / 128);
    // layer 1 (D=256 input)
    agg_kernel<FIN_D><<<NT / 8, 256, 0, stream>>>(XB, row_start, csr_src, H0);
    gemm_mfma<<<gemm_grid, 256, 0, stream>>>(H0, wt11, b11, H1, FIN_D, HID_D);   // overwrites XB (dead)
    gemm_mfma<<<gemm_grid, 256, 0, stream>>>(H1, wt12, b12, H0, HID_D, HID_D);
    // layer 2
    agg_kernel<HID_D><<<NT / 4, 256, 0, stream>>>(H0, row_start, csr_src, H1);
    gemm_mfma<<<gemm_grid, 256, 0, stream>>>(H1, wt21, b21, H0, HID_D, HID_D);
    gemm_mfma<<<gemm_grid, 256, 0, stream>>>(H0, wt22, b22, H1, HID_D, HID_D);
    // layer 3
    agg_kernel<HID_D><<<NT / 4, 256, 0, stream>>>(H1, row_start, csr_src, H0);
    gemm_mfma<<<gemm_grid, 256, 0, stream>>>(H0, wt31, b31, H1, HID_D, HID_D);
    gemm_mfma<<<gemm_grid, 256, 0, stream>>>(H1, wt32, b32, H0, HID_D, HID_D);
    // final linear [NT,512] -> [NT,2]
    lin_kernel<<<(NT + 3) / 4, 256, 0, stream>>>(H0, lw, lb, o, NT);

    // ---- distance + radix-select top-k ----
    dist_kernel<<<(N1 + 255) / 256, 256, 0, stream>>>(o, dist);
    hipMemsetAsync(selblk, 0, (4096 + 64) * sizeof(int), stream);
    histd_kernel<<<(N1 + 255) / 256, 256, 0, stream>>>(dist, hist);
    selk_kernel<<<1, 256, 0, stream>>>(hist, selout);
    compact_kernel<<<(N1 + 255) / 256, 256, 0, stream>>>(dist, selout, nc, cd, ci);
    rankc_kernel<<<(N1 + 255) / 256, 256, 0, stream>>>(cd, ci, nc, vals);

    // ---- head MLP ----
    head_kernel<<<1, 512, 0, stream>>>(vals, fc1w, fc1b, ln1g, ln1b,
                                       fc2w, fc2b, ln2g, ln2b, fc3w, fc3b,
                                       (float*)d_out);
}